// Round 5
// baseline (1135.448 us; speedup 1.0000x reference)
//
#include <hip/hip_runtime.h>
#include <hip/hip_bf16.h>
#include <math.h>

#define NN 50000
#define NE 1600000
#define D 64
#define DE 32
#define H 4
#define DH 16
#define L 3

typedef __attribute__((ext_vector_type(8))) short bf16x8;
typedef __attribute__((ext_vector_type(8))) short s16x8;
typedef __attribute__((ext_vector_type(4))) float f32x4;

__device__ __forceinline__ short f2b(float f) {
    __hip_bfloat16 h = __float2bfloat16(f);
    short s;
    __builtin_memcpy(&s, &h, 2);
    return s;
}
__device__ __forceinline__ float b2f(unsigned short u) {
    unsigned int x = ((unsigned int)u) << 16;
    float f; __builtin_memcpy(&f, &x, 4); return f;
}
__device__ __forceinline__ float b2f_lo(unsigned int p) {
    unsigned int x = p << 16;
    float f; __builtin_memcpy(&f, &x, 4); return f;
}
__device__ __forceinline__ float b2f_hi(unsigned int p) {
    unsigned int x = p & 0xffff0000u;
    float f; __builtin_memcpy(&f, &x, 4); return f;
}

// ======================= CSR build (per launch) =======================

__global__ void deg_kernel(const int* __restrict__ dst, int* __restrict__ cnt) {
    int e = blockIdx.x * 256 + threadIdx.x;
    if (e >= NE) return;
    atomicAdd(&cnt[dst[e]], 1);
}

__global__ void block_sum_kernel(const int* __restrict__ cnt, int* __restrict__ bsum) {
    int b = blockIdx.x, t = threadIdx.x;
    int base = b * 1024 + t * 4;
    int s = 0;
#pragma unroll
    for (int i = 0; i < 4; i++) { int idx = base + i; if (idx < NN) s += cnt[idx]; }
#pragma unroll
    for (int off = 32; off; off >>= 1) s += __shfl_down(s, off);
    __shared__ int wsum[4];
    if ((t & 63) == 0) wsum[t >> 6] = s;
    __syncthreads();
    if (t == 0) bsum[b] = wsum[0] + wsum[1] + wsum[2] + wsum[3];
}

// one-wave exclusive prefix scan over nb (<=64) block sums
__global__ void scan_bsum_kernel(int* __restrict__ bsum, int nb) {
    int t = threadIdx.x;    // 64 threads
    int v = (t < nb) ? bsum[t] : 0;
    int x = v;
#pragma unroll
    for (int off = 1; off < 64; off <<= 1) {
        int y = __shfl_up(x, off);
        if (t >= off) x += y;
    }
    if (t < nb) bsum[t] = x - v;
}

__global__ void scan_block_kernel(const int* __restrict__ cnt, const int* __restrict__ bsum,
                                  int* __restrict__ offsets) {
    int b = blockIdx.x, t = threadIdx.x;
    int base = b * 1024 + t * 4;
    int v[4]; int s = 0;
#pragma unroll
    for (int i = 0; i < 4; i++) { int idx = base + i; v[i] = (idx < NN) ? cnt[idx] : 0; s += v[i]; }
    int lane = t & 63, w = t >> 6;
    int x = s;
#pragma unroll
    for (int off = 1; off < 64; off <<= 1) {
        int y = __shfl_up(x, off);
        if (lane >= off) x += y;
    }
    __shared__ int wsum[4];
    if (lane == 63) wsum[w] = x;
    __syncthreads();
    int woff = 0;
    for (int i = 0; i < w; i++) woff += wsum[i];
    int run = bsum[b] + woff + x - s;
#pragma unroll
    for (int i = 0; i < 4; i++) {
        int idx = base + i;
        if (idx < NN) offsets[idx] = run;
        run += v[i];
    }
}

// writes only sorted_eid (1 random 4B write/edge); sorted_src/dst are
// emitted coalesced by eperm from L2-hot gathers
__global__ void scatter_kernel(const int* __restrict__ dst,
                               const int* __restrict__ offsets,
                               int* __restrict__ cursor,
                               int* __restrict__ sorted_eid) {
    int e = blockIdx.x * 256 + threadIdx.x;
    if (e >= NE) return;
    int d0 = dst[e];
    int pos = atomicAdd(&cursor[d0], 1);
    sorted_eid[offsets[d0] + pos] = e;
}

// ---- permute pristine fp32 e into dst-sorted bf16 eb_s, fused layer-0
// edge bias, and emit sorted_src/dst (coalesced) ----
__global__ void eperm_kernel(const float* __restrict__ e32, const int* __restrict__ sorted_eid,
                             const int* __restrict__ src, const int* __restrict__ dst,
                             const float* __restrict__ We0,
                             unsigned short* __restrict__ eb_s,
                             float* __restrict__ ebias_s,
                             int* __restrict__ sorted_src,
                             int* __restrict__ sorted_dst) {
    int t = blockIdx.x * 256 + threadIdx.x;
    if (t >= NE * 4) return;
    int p = t >> 2;
    int c = (t & 3) * 8;
    int eid = sorted_eid[p];
    const float* ep = e32 + (size_t)eid * DE + c;
    float4 x0 = *(const float4*)(ep);
    float4 x1 = *(const float4*)(ep + 4);
    float e8[8] = {x0.x, x0.y, x0.z, x0.w, x1.x, x1.y, x1.z, x1.w};
    s16x8 ob;
#pragma unroll
    for (int i = 0; i < 8; i++) ob[i] = f2b(e8[i]);
    *(s16x8*)(eb_s + (size_t)p * DE + c) = ob;
    // fused layer-0 bias: partial dot over this thread's 8 cols, reduce over
    // the 4 threads (consecutive lanes) of this edge
    float p0 = 0.f, p1 = 0.f, p2 = 0.f, p3 = 0.f;
#pragma unroll
    for (int i = 0; i < 8; i++) {
        float4 w = *(const float4*)(We0 + (c + i) * 4);
        p0 += e8[i] * w.x; p1 += e8[i] * w.y; p2 += e8[i] * w.z; p3 += e8[i] * w.w;
    }
#pragma unroll
    for (int off = 1; off < 4; off <<= 1) {
        p0 += __shfl_xor(p0, off, 4);
        p1 += __shfl_xor(p1, off, 4);
        p2 += __shfl_xor(p2, off, 4);
        p3 += __shfl_xor(p3, off, 4);
    }
    if ((t & 3) == 0) {
        float4 o; o.x = p0; o.y = p1; o.z = p2; o.w = p3;
        *(float4*)(ebias_s + (size_t)p * H) = o;
        sorted_src[p] = src[eid];
        sorted_dst[p] = dst[eid];
    }
}

// ---- Wem[L][160][32] fp32 -> Wt[L][32][160] bf16 (transposed) ----
__global__ void wconv_kernel(const float* __restrict__ Wem, unsigned short* __restrict__ Wt) {
    int t = blockIdx.x * 256 + threadIdx.x;
    if (t >= L * 32 * 160) return;
    int l = t / 5120;
    int r = t % 5120;
    int n = r / 160;
    int k = r % 160;
    Wt[t] = (unsigned short)f2b(Wem[l * 5120 + k * 32 + n]);
}

// ---- Wq/Wk/Wv/Wo -> transposed bf16 hi/lo split: WT[l][mat][n][k] ----
__global__ void wsplit_kernel(const float* __restrict__ Wq, const float* __restrict__ Wk,
                              const float* __restrict__ Wv, const float* __restrict__ Wo,
                              unsigned short* __restrict__ WT_hi,
                              unsigned short* __restrict__ WT_lo) {
    int t = blockIdx.x * 256 + threadIdx.x;
    if (t >= L * 4 * 64 * 64) return;
    int k = t & 63;
    int n = (t >> 6) & 63;
    int mat = (t >> 12) & 3;
    int l = t >> 14;
    const float* W = (mat == 0) ? Wq : (mat == 1) ? Wk : (mat == 2) ? Wv : Wo;
    float w = W[l * 4096 + k * 64 + n];
    unsigned short hi = (unsigned short)f2b(w);
    float lo = w - b2f(hi);
    WT_hi[t] = hi;
    WT_lo[t] = (unsigned short)f2b(lo);
}

// ---- h = node_features (fp32) + hb = bf16(node_features) ----
__global__ void hconv_kernel(const float* __restrict__ nf, float* __restrict__ h,
                             unsigned short* __restrict__ hb) {
    int t = blockIdx.x * 256 + threadIdx.x;
    if (t >= NN * D) return;
    float x = nf[t];
    h[t] = x;
    hb[t] = (unsigned short)f2b(x);
}

// ======================= per-layer kernels =======================

// ---- q = (h@Wq)*0.25 ; kv = pack(bf16(k), bf16(v)) via bf16x3 MFMA ----
__global__ __launch_bounds__(256, 8)
void qkv_kernel(const float* __restrict__ h,
                const unsigned short* __restrict__ WT_hi,   // this layer: [4][64][64]
                const unsigned short* __restrict__ WT_lo,
                float* __restrict__ q, unsigned int* __restrict__ kv) {
    int lane = threadIdx.x & 63;
    int wv = threadIdx.x >> 6;
    int m = lane & 15, quad = lane >> 4;
    int base = blockIdx.x * 16;

    const float* hp = h + (size_t)(base + m) * D + quad * 8;
    float af[16];
    *(f32x4*)&af[0]  = *(const f32x4*)(hp);
    *(f32x4*)&af[4]  = *(const f32x4*)(hp + 4);
    *(f32x4*)&af[8]  = *(const f32x4*)(hp + 32);
    *(f32x4*)&af[12] = *(const f32x4*)(hp + 36);
    bf16x8 a0h, a0l, a1h, a1l;
#pragma unroll
    for (int j = 0; j < 8; j++) {
        short h0 = f2b(af[j]);
        short h1 = f2b(af[8 + j]);
        a0h[j] = h0; a0l[j] = f2b(af[j] - b2f((unsigned short)h0));
        a1h[j] = h1; a1l[j] = f2b(af[8 + j] - b2f((unsigned short)h1));
    }

    f32x4 acc[3];
#pragma unroll
    for (int mat = 0; mat < 3; mat++) {
        const unsigned short* bh = WT_hi + ((size_t)mat * 64 + wv * 16 + m) * 64 + quad * 8;
        const unsigned short* bl = WT_lo + ((size_t)mat * 64 + wv * 16 + m) * 64 + quad * 8;
        bf16x8 bh0 = *(const bf16x8*)(bh);
        bf16x8 bh1 = *(const bf16x8*)(bh + 32);
        bf16x8 bl0 = *(const bf16x8*)(bl);
        bf16x8 bl1 = *(const bf16x8*)(bl + 32);
        f32x4 c = {0.f, 0.f, 0.f, 0.f};
        c = __builtin_amdgcn_mfma_f32_16x16x32_bf16(a0h, bh0, c, 0, 0, 0);
        c = __builtin_amdgcn_mfma_f32_16x16x32_bf16(a1h, bh1, c, 0, 0, 0);
        c = __builtin_amdgcn_mfma_f32_16x16x32_bf16(a0h, bl0, c, 0, 0, 0);
        c = __builtin_amdgcn_mfma_f32_16x16x32_bf16(a1h, bl1, c, 0, 0, 0);
        c = __builtin_amdgcn_mfma_f32_16x16x32_bf16(a0l, bh0, c, 0, 0, 0);
        c = __builtin_amdgcn_mfma_f32_16x16x32_bf16(a1l, bh1, c, 0, 0, 0);
        acc[mat] = c;
    }

#pragma unroll
    for (int reg = 0; reg < 4; reg++) {
        int row = base + quad * 4 + reg;
        int col = wv * 16 + m;
        q[(size_t)row * D + col] = acc[0][reg] * 0.25f;
        unsigned int kb = (unsigned short)f2b(acc[1][reg]);
        unsigned int vb = (unsigned short)f2b(acc[2][reg]);
        kv[(size_t)row * D + col] = (vb << 16) | kb;
    }
}

// ---- fused per-dst-node online-softmax attention + aggregation (8-wide) ----
__global__ void attn_kernel(const float* __restrict__ q, const unsigned int* __restrict__ kv,
                            const float* __restrict__ ebias_s,
                            const int* __restrict__ sorted_src,
                            const int* __restrict__ offsets,
                            float* __restrict__ agg) {
    int node = blockIdx.x * 4 + threadIdx.y;
    node = __builtin_amdgcn_readfirstlane(node);
    if (node >= NN) return;
    int lane = threadIdx.x;
    int hh = lane >> 4;
    float qv = q[node * D + lane];
    int beg = offsets[node];
    int end = (node == NN - 1) ? NE : offsets[node + 1];
    float mmax = -INFINITY, den = 0.f, acc = 0.f;
    int i = beg;
    for (; i + 8 <= end; i += 8) {
        int ss[8]; unsigned int kk8[8]; float bb8[8], dd[8];
#pragma unroll
        for (int u = 0; u < 8; u++) ss[u] = sorted_src[i + u];
#pragma unroll
        for (int u = 0; u < 8; u++) kk8[u] = kv[ss[u] * D + lane];
#pragma unroll
        for (int u = 0; u < 8; u++) bb8[u] = ebias_s[(i + u) * H + hh];
#pragma unroll
        for (int u = 0; u < 8; u++) dd[u] = qv * b2f_lo(kk8[u]);
#pragma unroll
        for (int off = 1; off < 16; off <<= 1) {
#pragma unroll
            for (int u = 0; u < 8; u++) dd[u] += __shfl_xor(dd[u], off, 16);
        }
        float nm = mmax;
#pragma unroll
        for (int u = 0; u < 8; u++) { dd[u] += bb8[u]; nm = fmaxf(nm, dd[u]); }
        float scale = __expf(mmax - nm);
        float ps = 0.f, av = 0.f;
#pragma unroll
        for (int u = 0; u < 8; u++) {
            float p = __expf(dd[u] - nm);
            ps += p;
            av += p * b2f_hi(kk8[u]);
        }
        den = den * scale + ps;
        acc = acc * scale + av;
        mmax = nm;
    }
    for (; i < end; i++) {
        int s = sorted_src[i];
        unsigned int kvv = kv[s * D + lane];
        float b = ebias_s[i * H + hh];
        float dot = qv * b2f_lo(kvv);
#pragma unroll
        for (int off = 1; off < 16; off <<= 1) dot += __shfl_xor(dot, off, 16);
        float score = dot + b;
        float nm = fmaxf(mmax, score);
        float scale = __expf(mmax - nm);
        float p = __expf(score - nm);
        den = den * scale + p;
        acc = acc * scale + p * b2f_hi(kvv);
        mmax = nm;
    }
    agg[node * D + lane] = acc / (den + 1e-9f);
}

// ---- h = LN(h + agg @ Wo) + bf16 shadow ; agg@Wo via bf16x3 MFMA ----
__global__ __launch_bounds__(256, 8)
void node_update_kernel(float* __restrict__ h, const float* __restrict__ agg,
                        const unsigned short* __restrict__ WoT_hi,   // [64][64]
                        const unsigned short* __restrict__ WoT_lo,
                        const float* __restrict__ gn,
                        const float* __restrict__ bn,
                        unsigned short* __restrict__ hb) {
    __shared__ float sx[16][68];
    int lane = threadIdx.x & 63;
    int wv = threadIdx.x >> 6;
    int m = lane & 15, quad = lane >> 4;
    int base = blockIdx.x * 16;

    const float* ap = agg + (size_t)(base + m) * D + quad * 8;
    float af[16];
    *(f32x4*)&af[0]  = *(const f32x4*)(ap);
    *(f32x4*)&af[4]  = *(const f32x4*)(ap + 4);
    *(f32x4*)&af[8]  = *(const f32x4*)(ap + 32);
    *(f32x4*)&af[12] = *(const f32x4*)(ap + 36);
    bf16x8 a0h, a0l, a1h, a1l;
#pragma unroll
    for (int j = 0; j < 8; j++) {
        short h0 = f2b(af[j]);
        short h1 = f2b(af[8 + j]);
        a0h[j] = h0; a0l[j] = f2b(af[j] - b2f((unsigned short)h0));
        a1h[j] = h1; a1l[j] = f2b(af[8 + j] - b2f((unsigned short)h1));
    }
    const unsigned short* bh = WoT_hi + ((size_t)wv * 16 + m) * 64 + quad * 8;
    const unsigned short* bl = WoT_lo + ((size_t)wv * 16 + m) * 64 + quad * 8;
    bf16x8 bh0 = *(const bf16x8*)(bh);
    bf16x8 bh1 = *(const bf16x8*)(bh + 32);
    bf16x8 bl0 = *(const bf16x8*)(bl);
    bf16x8 bl1 = *(const bf16x8*)(bl + 32);
    f32x4 c = {0.f, 0.f, 0.f, 0.f};
    c = __builtin_amdgcn_mfma_f32_16x16x32_bf16(a0h, bh0, c, 0, 0, 0);
    c = __builtin_amdgcn_mfma_f32_16x16x32_bf16(a1h, bh1, c, 0, 0, 0);
    c = __builtin_amdgcn_mfma_f32_16x16x32_bf16(a0h, bl0, c, 0, 0, 0);
    c = __builtin_amdgcn_mfma_f32_16x16x32_bf16(a1h, bl1, c, 0, 0, 0);
    c = __builtin_amdgcn_mfma_f32_16x16x32_bf16(a0l, bh0, c, 0, 0, 0);
    c = __builtin_amdgcn_mfma_f32_16x16x32_bf16(a1l, bh1, c, 0, 0, 0);

#pragma unroll
    for (int reg = 0; reg < 4; reg++) {
        int row = quad * 4 + reg;
        int col = wv * 16 + m;
        sx[row][col] = c[reg] + h[(size_t)(base + row) * D + col];
    }
    __syncthreads();

    float gcol = gn[lane], bcol = bn[lane];
#pragma unroll
    for (int it = 0; it < 4; it++) {
        int ln = wv * 4 + it;
        int node = base + ln;
        float x = sx[ln][lane];
        float sum = x, sq = x * x;
#pragma unroll
        for (int off = 32; off; off >>= 1) {
            sum += __shfl_xor(sum, off);
            sq += __shfl_xor(sq, off);
        }
        float mu = sum * (1.f / 64.f);
        float var = sq * (1.f / 64.f) - mu * mu;
        float out = (x - mu) * rsqrtf(var + 1e-5f) * gcol + bcol;
        h[(size_t)node * D + lane] = out;
        hb[(size_t)node * D + lane] = (unsigned short)f2b(out);
    }
}

// ---- e = LN(e + gelu([h[src]|h[dst]|e] @ Wem + bem)) via bf16 MFMA.
// v4: weights in REGISTERS (10 B-frags, loaded once per wave from L2-hot
// global) — no LDS staging, no div/mod address math, ZERO block barriers
// (ytr transpose buffer is per-wave private; same-wave LDS ordering is
// compiler-enforced via lgkmcnt). 256 edges/block, 64/wave: per-wave fixed
// costs amortize 4x, waves drift freely.
__global__ __launch_bounds__(256, 4)
void edge_update_mfma_kernel(const unsigned short* __restrict__ hb,
                             unsigned short* __restrict__ eb_s,
                             const int* __restrict__ sorted_src,
                             const int* __restrict__ sorted_dst,
                             const unsigned short* __restrict__ Wt,   // [32][160] bf16
                             const float* __restrict__ bem,
                             const float* __restrict__ ge,
                             const float* __restrict__ be,
                             const float* __restrict__ We_next,       // [32][4]
                             float* __restrict__ ebias_s,
                             int do_bias, int do_estore) {
    __shared__ __align__(16) float ytr[4][16][36];   // per-wave private
    int tid = threadIdx.x;
    int wave = tid >> 6;
    int lane = tid & 63;
    int wbase = blockIdx.x * 256 + wave * 64;    // 64 edges per wave
    int m = lane & 15;
    int quad = lane >> 4;

    // weight B-fragments in registers, once per wave
    const unsigned short* w0 = Wt + m * 160 + quad * 8;
    const unsigned short* w1 = Wt + (m + 16) * 160 + quad * 8;
    bf16x8 B0[5], B1[5];
#pragma unroll
    for (int ks = 0; ks < 5; ks++) {
        B0[ks] = *(const bf16x8*)(w0 + ks * 32);
        B1[ks] = *(const bf16x8*)(w1 + ks * 32);
    }
    // B-fragment of We_next (bias MFMA)
    bf16x8 wb;
#pragma unroll
    for (int j = 0; j < 8; j++) {
        float w = (do_bias && m < 4) ? We_next[(quad * 8 + j) * 4 + m] : 0.f;
        wb[j] = f2b(w);
    }
    float bm0 = bem[m], bm1 = bem[m + 16];
    float4 g0v = *(const float4*)(ge + quad * 8);
    float4 g1v = *(const float4*)(ge + quad * 8 + 4);
    float4 b0v = *(const float4*)(be + quad * 8);
    float4 b1v = *(const float4*)(be + quad * 8 + 4);
    float gg[8] = {g0v.x, g0v.y, g0v.z, g0v.w, g1v.x, g1v.y, g1v.z, g1v.w};
    float bbv[8] = {b0v.x, b0v.y, b0v.z, b0v.w, b1v.x, b1v.y, b1v.z, b1v.w};

    for (int g = 0; g < 4; g++) {
        int we = wbase + g * 16;
        int p_m = we + m;
        int s_idx = sorted_src[p_m], d_idx = sorted_dst[p_m];
        const unsigned short* as = hb + (size_t)s_idx * D + quad * 8;
        const unsigned short* ad = hb + (size_t)d_idx * D + quad * 8;
        bf16x8 a_s0 = *(const bf16x8*)(as);
        bf16x8 a_s1 = *(const bf16x8*)(as + 32);
        bf16x8 a_d0 = *(const bf16x8*)(ad);
        bf16x8 a_d1 = *(const bf16x8*)(ad + 32);
        bf16x8 ea = *(const bf16x8*)(eb_s + (size_t)p_m * DE + quad * 8);

        f32x4 c0 = {0.f, 0.f, 0.f, 0.f};
        f32x4 c1 = {0.f, 0.f, 0.f, 0.f};
#pragma unroll
        for (int ks = 0; ks < 4; ks++) {
            bf16x8 a = (ks == 0) ? a_s0 : (ks == 1) ? a_s1 : (ks == 2) ? a_d0 : a_d1;
            c0 = __builtin_amdgcn_mfma_f32_16x16x32_bf16(a, B0[ks], c0, 0, 0, 0);
            c1 = __builtin_amdgcn_mfma_f32_16x16x32_bf16(a, B1[ks], c1, 0, 0, 0);
        }
        c0 = __builtin_amdgcn_mfma_f32_16x16x32_bf16(ea, B0[4], c0, 0, 0, 0);
        c1 = __builtin_amdgcn_mfma_f32_16x16x32_bf16(ea, B1[4], c1, 0, 0, 0);

        // gelu(mfma + bem) in C-layout (col=m / m+16, row=quad*4+reg) -> LDS
#pragma unroll
        for (int reg = 0; reg < 4; reg++) {
            int row = quad * 4 + reg;
            float y0 = c0[reg] + bm0;
            float y1 = c1[reg] + bm1;
            float u0 = 1.5957691216057308f * (y0 + 0.044715f * y0 * y0 * y0);
            float u1 = 1.5957691216057308f * (y1 + 0.044715f * y1 * y1 * y1);
            float t0 = 1.f - 2.f / (1.f + __expf(u0));
            float t1 = 1.f - 2.f / (1.f + __expf(u1));
            ytr[wave][row][m] = 0.5f * y0 * (1.f + t0);
            ytr[wave][row][m + 16] = 0.5f * y1 * (1.f + t1);
        }
        // same-wave LDS write->read: ordering enforced by lgkmcnt, no barrier

        // row-owned: lane handles edge (we+m), cols quad*8..+8
        float y[8];
        *(f32x4*)&y[0] = *(const f32x4*)&ytr[wave][m][quad * 8];
        *(f32x4*)&y[4] = *(const f32x4*)&ytr[wave][m][quad * 8 + 4];
        float s = 0.f, sq = 0.f;
#pragma unroll
        for (int j = 0; j < 8; j++) {
            y[j] += b2f((unsigned short)ea[j]);      // residual (from A-frag)
            s += y[j];
            sq += y[j] * y[j];
        }
        s += __shfl_xor(s, 16); s += __shfl_xor(s, 32);
        sq += __shfl_xor(sq, 16); sq += __shfl_xor(sq, 32);
        float mu = s * (1.f / 32.f);
        float var = sq * (1.f / 32.f) - mu * mu;
        float inv = rsqrtf(var + 1e-5f);

        bf16x8 zb;
#pragma unroll
        for (int j = 0; j < 8; j++) {
            float z = (y[j] - mu) * inv * gg[j] + bbv[j];
            zb[j] = f2b(z);
        }
        if (do_estore) {
            *(s16x8*)(eb_s + (size_t)p_m * DE + quad * 8) = zb;
        }
        if (do_bias) {
            f32x4 db = {0.f, 0.f, 0.f, 0.f};
            db = __builtin_amdgcn_mfma_f32_16x16x32_bf16(zb, wb, db, 0, 0, 0);
            if (m < 4) {
#pragma unroll
                for (int reg = 0; reg < 4; reg++) {
                    ebias_s[(we + quad * 4 + reg) * H + m] = db[reg];
                }
            }
        }
    }
}

extern "C" void kernel_launch(void* const* d_in, const int* in_sizes, int n_in,
                              void* d_out, int out_size, void* d_ws, size_t ws_size,
                              hipStream_t stream) {
    const float* node_features = (const float*)d_in[0];
    const float* e = (const float*)d_in[1];   // pristine fp32 e (read-only)
    const int* edge_index = (const int*)d_in[2];
    const int* src = edge_index;
    const int* dst = edge_index + NE;
    const float* Wq = (const float*)d_in[3];
    const float* Wk = (const float*)d_in[4];
    const float* Wv = (const float*)d_in[5];
    const float* Wo = (const float*)d_in[6];
    const float* We = (const float*)d_in[7];
    const float* Wem = (const float*)d_in[8];
    const float* bem = (const float*)d_in[9];
    const float* gn = (const float*)d_in[10];
    const float* bn = (const float*)d_in[11];
    const float* ge = (const float*)d_in[12];
    const float* be = (const float*)d_in[13];

    float* h = (float*)d_out;       // h lives in d_out

    float* ws = (float*)d_ws;
    float* q = ws;                                       // N*D f32
    unsigned int* kv = (unsigned int*)(q + NN * D);      // N*D u32 (packed bf16 k|v)
    float* agg = (float*)(kv + NN * D);                  // N*D f32
    float* ebias_s = agg + NN * D;                       // E*H f32 (sorted order)
    int* offsets = (int*)(ebias_s + (size_t)NE * H);     // NN
    int* cursor = offsets + NN;                          // NN
    int* bsum = cursor + NN;                             // 64
    int* sorted_eid = bsum + 64;                         // NE
    int* sorted_src = sorted_eid + NE;                   // NE
    int* sorted_dst = sorted_src + NE;                   // NE
    unsigned short* Wt = (unsigned short*)(sorted_dst + NE);  // L*32*160 bf16
    unsigned short* hb = Wt + L * 32 * 160;              // N*D bf16
    unsigned short* eb_s = hb + NN * D;                  // E*DE bf16 e-state (sorted)
    unsigned short* WT_hi = eb_s + (size_t)NE * DE;      // L*4*64*64 bf16
    unsigned short* WT_lo = WT_hi + L * 4 * 64 * 64;     // L*4*64*64 bf16

    const int NB = (NN + 1023) / 1024;

    // ---- CSR build + preconverts (inputs constant; rebuilt every launch) ----
    hipMemsetAsync(cursor, 0, NN * sizeof(int), stream);
    deg_kernel<<<(NE + 255) / 256, 256, 0, stream>>>(dst, cursor);
    block_sum_kernel<<<NB, 256, 0, stream>>>(cursor, bsum);
    scan_bsum_kernel<<<1, 64, 0, stream>>>(bsum, NB);
    scan_block_kernel<<<NB, 256, 0, stream>>>(cursor, bsum, offsets);
    hipMemsetAsync(cursor, 0, NN * sizeof(int), stream);
    scatter_kernel<<<(NE + 255) / 256, 256, 0, stream>>>(dst, offsets, cursor, sorted_eid);
    // eperm produces eb_s, layer-0 bias, and sorted_src/dst (coalesced)
    eperm_kernel<<<(NE * 4 + 255) / 256, 256, 0, stream>>>(e, sorted_eid, src, dst, We,
                                                           eb_s, ebias_s,
                                                           sorted_src, sorted_dst);
    wconv_kernel<<<(L * 32 * 160 + 255) / 256, 256, 0, stream>>>(Wem, Wt);
    wsplit_kernel<<<(L * 4 * 64 * 64 + 255) / 256, 256, 0, stream>>>(Wq, Wk, Wv, Wo,
                                                                     WT_hi, WT_lo);
    hconv_kernel<<<(NN * D + 255) / 256, 256, 0, stream>>>(node_features, h, hb);

    for (int layer = 0; layer < L; layer++) {
        const unsigned short* WT_hi_l = WT_hi + (size_t)layer * 4 * 4096;
        const unsigned short* WT_lo_l = WT_lo + (size_t)layer * 4 * 4096;
        const unsigned short* Wt_l = Wt + layer * 32 * 160;
        const float* bem_l = bem + layer * DE;
        const float* gn_l = gn + layer * D;
        const float* bn_l = bn + layer * D;
        const float* ge_l = ge + layer * DE;
        const float* be_l = be + layer * DE;

        qkv_kernel<<<NN / 16, 256, 0, stream>>>(h, WT_hi_l, WT_lo_l, q, kv);
        attn_kernel<<<NN / 4, dim3(64, 4), 0, stream>>>(q, kv, ebias_s, sorted_src,
                                                        offsets, agg);
        node_update_kernel<<<NN / 16, 256, 0, stream>>>(h, agg,
                                                        WT_hi_l + 3 * 4096,
                                                        WT_lo_l + 3 * 4096,
                                                        gn_l, bn_l, hb);
        // layer 0: full edge update; layer 1: bias-only; layer 2: skipped
        if (layer < L - 1) {
            const float* We_next = We + (layer + 1) * DE * H;
            edge_update_mfma_kernel<<<NE / 256, 256, 0, stream>>>(hb, eb_s, sorted_src,
                                                                  sorted_dst, Wt_l,
                                                                  bem_l, ge_l, be_l,
                                                                  We_next, ebias_s,
                                                                  1, layer == 0 ? 1 : 0);
        }
    }
}

// Round 6
// 1112.564 us; speedup vs baseline: 1.0206x; 1.0206x over previous
//
#include <hip/hip_runtime.h>
#include <hip/hip_bf16.h>
#include <math.h>

#define NN 50000
#define NE 1600000
#define D 64
#define DE 32
#define H 4
#define DH 16
#define L 3

typedef __attribute__((ext_vector_type(8))) short bf16x8;
typedef __attribute__((ext_vector_type(8))) short s16x8;
typedef __attribute__((ext_vector_type(4))) float f32x4;
typedef __attribute__((ext_vector_type(4))) unsigned int u32x4;

__device__ __forceinline__ short f2b(float f) {
    __hip_bfloat16 h = __float2bfloat16(f);
    short s;
    __builtin_memcpy(&s, &h, 2);
    return s;
}
__device__ __forceinline__ float b2f(unsigned short u) {
    unsigned int x = ((unsigned int)u) << 16;
    float f; __builtin_memcpy(&f, &x, 4); return f;
}
__device__ __forceinline__ float b2f_lo(unsigned int p) {
    unsigned int x = p << 16;
    float f; __builtin_memcpy(&f, &x, 4); return f;
}
__device__ __forceinline__ float b2f_hi(unsigned int p) {
    unsigned int x = p & 0xffff0000u;
    float f; __builtin_memcpy(&f, &x, 4); return f;
}

// ======================= CSR build (per launch) =======================

__global__ void deg_kernel(const int* __restrict__ dst, int* __restrict__ cnt) {
    int e = blockIdx.x * 256 + threadIdx.x;
    if (e >= NE) return;
    atomicAdd(&cnt[dst[e]], 1);
}

__global__ void block_sum_kernel(const int* __restrict__ cnt, int* __restrict__ bsum) {
    int b = blockIdx.x, t = threadIdx.x;
    int base = b * 1024 + t * 4;
    int s = 0;
#pragma unroll
    for (int i = 0; i < 4; i++) { int idx = base + i; if (idx < NN) s += cnt[idx]; }
#pragma unroll
    for (int off = 32; off; off >>= 1) s += __shfl_down(s, off);
    __shared__ int wsum[4];
    if ((t & 63) == 0) wsum[t >> 6] = s;
    __syncthreads();
    if (t == 0) bsum[b] = wsum[0] + wsum[1] + wsum[2] + wsum[3];
}

// one-wave exclusive prefix scan over nb (<=64) block sums
__global__ void scan_bsum_kernel(int* __restrict__ bsum, int nb) {
    int t = threadIdx.x;    // 64 threads
    int v = (t < nb) ? bsum[t] : 0;
    int x = v;
#pragma unroll
    for (int off = 1; off < 64; off <<= 1) {
        int y = __shfl_up(x, off);
        if (t >= off) x += y;
    }
    if (t < nb) bsum[t] = x - v;
}

// writes offsets AND re-initializes cursor(=cnt array) to the offsets,
// so scatter can atomicAdd on it directly (no second memset, no offsets read)
__global__ void scan_block_kernel(int* __restrict__ cnt, const int* __restrict__ bsum,
                                  int* __restrict__ offsets) {
    int b = blockIdx.x, t = threadIdx.x;
    int base = b * 1024 + t * 4;
    int v[4]; int s = 0;
#pragma unroll
    for (int i = 0; i < 4; i++) { int idx = base + i; v[i] = (idx < NN) ? cnt[idx] : 0; s += v[i]; }
    int lane = t & 63, w = t >> 6;
    int x = s;
#pragma unroll
    for (int off = 1; off < 64; off <<= 1) {
        int y = __shfl_up(x, off);
        if (lane >= off) x += y;
    }
    __shared__ int wsum[4];
    if (lane == 63) wsum[w] = x;
    __syncthreads();
    int woff = 0;
    for (int i = 0; i < w; i++) woff += wsum[i];
    int run = bsum[b] + woff + x - s;
#pragma unroll
    for (int i = 0; i < 4; i++) {
        int idx = base + i;
        if (idx < NN) { offsets[idx] = run; cnt[idx] = run; }
        run += v[i];
    }
}

// packed {eid, src} random 8B write (same dirty-line count as a 4B write);
// src read contiguously here so no random src gather is needed later
__global__ void scatter_kernel(const int* __restrict__ src, const int* __restrict__ dst,
                               int* __restrict__ cursor,
                               int2* __restrict__ sorted_es) {
    int e = blockIdx.x * 256 + threadIdx.x;
    if (e >= NE) return;
    int d0 = dst[e];
    int pos = atomicAdd(&cursor[d0], 1);
    int2 v; v.x = e; v.y = src[e];
    sorted_es[pos] = v;
}

// sorted_dst derived from offsets: node n fills its contiguous range
__global__ void fill_dst_kernel(const int* __restrict__ offsets, int* __restrict__ sorted_dst) {
    int n = blockIdx.x * 256 + threadIdx.x;
    if (n >= NN) return;
    int b = offsets[n];
    int e = (n == NN - 1) ? NE : offsets[n + 1];
    for (int i = b; i < e; i++) sorted_dst[i] = n;
}

// ---- permute pristine fp32 e into dst-sorted bf16 eb_s + fused layer-0
// edge bias (from the pristine fp32 values). Only compulsory traffic now. ----
__global__ void eperm_kernel(const float* __restrict__ e32, const int2* __restrict__ sorted_es,
                             const float* __restrict__ We0,
                             unsigned short* __restrict__ eb_s,
                             float* __restrict__ ebias_s) {
    int t = blockIdx.x * 256 + threadIdx.x;
    if (t >= NE * 4) return;
    int p = t >> 2;
    int c = (t & 3) * 8;
    int eid = sorted_es[p].x;
    const float* ep = e32 + (size_t)eid * DE + c;
    float4 x0 = *(const float4*)(ep);
    float4 x1 = *(const float4*)(ep + 4);
    float e8[8] = {x0.x, x0.y, x0.z, x0.w, x1.x, x1.y, x1.z, x1.w};
    s16x8 ob;
#pragma unroll
    for (int i = 0; i < 8; i++) ob[i] = f2b(e8[i]);
    *(s16x8*)(eb_s + (size_t)p * DE + c) = ob;
    float p0 = 0.f, p1 = 0.f, p2 = 0.f, p3 = 0.f;
#pragma unroll
    for (int i = 0; i < 8; i++) {
        float4 w = *(const float4*)(We0 + (c + i) * 4);
        p0 += e8[i] * w.x; p1 += e8[i] * w.y; p2 += e8[i] * w.z; p3 += e8[i] * w.w;
    }
#pragma unroll
    for (int off = 1; off < 4; off <<= 1) {
        p0 += __shfl_xor(p0, off, 4);
        p1 += __shfl_xor(p1, off, 4);
        p2 += __shfl_xor(p2, off, 4);
        p3 += __shfl_xor(p3, off, 4);
    }
    if ((t & 3) == 0) {
        float4 o; o.x = p0; o.y = p1; o.z = p2; o.w = p3;
        *(float4*)(ebias_s + (size_t)p * H) = o;
    }
}

// ---- Wem[L][160][32] fp32 -> Wt[L][32][160] bf16 (transposed) ----
__global__ void wconv_kernel(const float* __restrict__ Wem, unsigned short* __restrict__ Wt) {
    int t = blockIdx.x * 256 + threadIdx.x;
    if (t >= L * 32 * 160) return;
    int l = t / 5120;
    int r = t % 5120;
    int n = r / 160;
    int k = r % 160;
    Wt[t] = (unsigned short)f2b(Wem[l * 5120 + k * 32 + n]);
}

// ---- Wq/Wk/Wv/Wo -> transposed bf16 hi/lo split: WT[l][mat][n][k] ----
__global__ void wsplit_kernel(const float* __restrict__ Wq, const float* __restrict__ Wk,
                              const float* __restrict__ Wv, const float* __restrict__ Wo,
                              unsigned short* __restrict__ WT_hi,
                              unsigned short* __restrict__ WT_lo) {
    int t = blockIdx.x * 256 + threadIdx.x;
    if (t >= L * 4 * 64 * 64) return;
    int k = t & 63;
    int n = (t >> 6) & 63;
    int mat = (t >> 12) & 3;
    int l = t >> 14;
    const float* W = (mat == 0) ? Wq : (mat == 1) ? Wk : (mat == 2) ? Wv : Wo;
    float w = W[l * 4096 + k * 64 + n];
    unsigned short hi = (unsigned short)f2b(w);
    float lo = w - b2f(hi);
    WT_hi[t] = hi;
    WT_lo[t] = (unsigned short)f2b(lo);
}

// ---- h = node_features (fp32) + hb = bf16(node_features) ----
__global__ void hconv_kernel(const float* __restrict__ nf, float* __restrict__ h,
                             unsigned short* __restrict__ hb) {
    int t = blockIdx.x * 256 + threadIdx.x;
    if (t >= NN * D) return;
    float x = nf[t];
    h[t] = x;
    hb[t] = (unsigned short)f2b(x);
}

// ======================= per-layer kernels =======================

// ---- q = (h@Wq)*0.25 ; kv = pack(bf16(k), bf16(v)) via bf16x3 MFMA ----
__global__ __launch_bounds__(256, 8)
void qkv_kernel(const float* __restrict__ h,
                const unsigned short* __restrict__ WT_hi,   // this layer: [4][64][64]
                const unsigned short* __restrict__ WT_lo,
                float* __restrict__ q, unsigned int* __restrict__ kv) {
    int lane = threadIdx.x & 63;
    int wv = threadIdx.x >> 6;
    int m = lane & 15, quad = lane >> 4;
    int base = blockIdx.x * 16;

    const float* hp = h + (size_t)(base + m) * D + quad * 8;
    float af[16];
    *(f32x4*)&af[0]  = *(const f32x4*)(hp);
    *(f32x4*)&af[4]  = *(const f32x4*)(hp + 4);
    *(f32x4*)&af[8]  = *(const f32x4*)(hp + 32);
    *(f32x4*)&af[12] = *(const f32x4*)(hp + 36);
    bf16x8 a0h, a0l, a1h, a1l;
#pragma unroll
    for (int j = 0; j < 8; j++) {
        short h0 = f2b(af[j]);
        short h1 = f2b(af[8 + j]);
        a0h[j] = h0; a0l[j] = f2b(af[j] - b2f((unsigned short)h0));
        a1h[j] = h1; a1l[j] = f2b(af[8 + j] - b2f((unsigned short)h1));
    }

    f32x4 acc[3];
#pragma unroll
    for (int mat = 0; mat < 3; mat++) {
        const unsigned short* bh = WT_hi + ((size_t)mat * 64 + wv * 16 + m) * 64 + quad * 8;
        const unsigned short* bl = WT_lo + ((size_t)mat * 64 + wv * 16 + m) * 64 + quad * 8;
        bf16x8 bh0 = *(const bf16x8*)(bh);
        bf16x8 bh1 = *(const bf16x8*)(bh + 32);
        bf16x8 bl0 = *(const bf16x8*)(bl);
        bf16x8 bl1 = *(const bf16x8*)(bl + 32);
        f32x4 c = {0.f, 0.f, 0.f, 0.f};
        c = __builtin_amdgcn_mfma_f32_16x16x32_bf16(a0h, bh0, c, 0, 0, 0);
        c = __builtin_amdgcn_mfma_f32_16x16x32_bf16(a1h, bh1, c, 0, 0, 0);
        c = __builtin_amdgcn_mfma_f32_16x16x32_bf16(a0h, bl0, c, 0, 0, 0);
        c = __builtin_amdgcn_mfma_f32_16x16x32_bf16(a1h, bl1, c, 0, 0, 0);
        c = __builtin_amdgcn_mfma_f32_16x16x32_bf16(a0l, bh0, c, 0, 0, 0);
        c = __builtin_amdgcn_mfma_f32_16x16x32_bf16(a1l, bh1, c, 0, 0, 0);
        acc[mat] = c;
    }

#pragma unroll
    for (int reg = 0; reg < 4; reg++) {
        int row = base + quad * 4 + reg;
        int col = wv * 16 + m;
        q[(size_t)row * D + col] = acc[0][reg] * 0.25f;
        unsigned int kb = (unsigned short)f2b(acc[1][reg]);
        unsigned int vb = (unsigned short)f2b(acc[2][reg]);
        kv[(size_t)row * D + col] = (vb << 16) | kb;
    }
}

// ---- attention v2: lane = (edge u, head h). Full 16-dim dot in registers
// (no per-iter cross-lane ops at all); exp without max-subtraction (softmax
// is shift-invariant; scores are O(1) since h,e are LN'd and weights ~0.05 —
// overflow needs score>88). Per-lane partial den/acc merged once per node
// via padded LDS transpose + 4 den shuffles. ----
__global__ __launch_bounds__(256, 8)
void attn_kernel(const float* __restrict__ q, const unsigned int* __restrict__ kv,
                 const float* __restrict__ ebias_s,
                 const int2* __restrict__ es,
                 const int* __restrict__ offsets,
                 float* __restrict__ agg) {
    __shared__ __align__(16) float sacc[4][4][16][20];   // [wave][head][u][j], pad 20
    int wave = threadIdx.y;
    int node = blockIdx.x * 4 + wave;
    node = __builtin_amdgcn_readfirstlane(node);
    if (node >= NN) return;
    int lane = threadIdx.x;
    int u = lane & 15, hh = lane >> 4;

    float qv[16];
    const float* qp = q + (size_t)node * D + hh * 16;
    *(f32x4*)&qv[0]  = *(const f32x4*)(qp);
    *(f32x4*)&qv[4]  = *(const f32x4*)(qp + 4);
    *(f32x4*)&qv[8]  = *(const f32x4*)(qp + 8);
    *(f32x4*)&qv[12] = *(const f32x4*)(qp + 12);

    int beg = offsets[node];
    int end = (node == NN - 1) ? NE : offsets[node + 1];
    float den = 0.f;
    float acc[16];
#pragma unroll
    for (int j = 0; j < 16; j++) acc[j] = 0.f;

    for (int i = beg; i < end; i += 16) {
        int idx = i + u;
        bool valid = idx < end;
        int sidx = valid ? idx : (end - 1);
        int s = es[sidx].y;
        float bias = ebias_s[sidx * H + hh];
        const unsigned int* kp = kv + (size_t)s * D + hh * 16;
        unsigned int kr[16];
        *(u32x4*)&kr[0]  = *(const u32x4*)(kp);
        *(u32x4*)&kr[4]  = *(const u32x4*)(kp + 4);
        *(u32x4*)&kr[8]  = *(const u32x4*)(kp + 8);
        *(u32x4*)&kr[12] = *(const u32x4*)(kp + 12);
        float dot = bias;
#pragma unroll
        for (int j = 0; j < 16; j++) dot += qv[j] * b2f_lo(kr[j]);
        float p = valid ? __expf(dot) : 0.f;
        den += p;
#pragma unroll
        for (int j = 0; j < 16; j++) acc[j] += p * b2f_hi(kr[j]);
    }

    // merge across the 16 lanes of this head group
    *(f32x4*)&sacc[wave][hh][u][0]  = *(const f32x4*)&acc[0];
    *(f32x4*)&sacc[wave][hh][u][4]  = *(const f32x4*)&acc[4];
    *(f32x4*)&sacc[wave][hh][u][8]  = *(const f32x4*)&acc[8];
    *(f32x4*)&sacc[wave][hh][u][12] = *(const f32x4*)&acc[12];
#pragma unroll
    for (int off = 1; off < 16; off <<= 1) den += __shfl_xor(den, off, 16);
    float o = 0.f;
#pragma unroll
    for (int u2 = 0; u2 < 16; u2++) o += sacc[wave][hh][u2][u];
    agg[(size_t)node * D + hh * 16 + u] = o / (den + 1e-9f);
}

// ---- h = LN(h + agg @ Wo) + bf16 shadow ; agg@Wo via bf16x3 MFMA ----
__global__ __launch_bounds__(256, 8)
void node_update_kernel(float* __restrict__ h, const float* __restrict__ agg,
                        const unsigned short* __restrict__ WoT_hi,   // [64][64]
                        const unsigned short* __restrict__ WoT_lo,
                        const float* __restrict__ gn,
                        const float* __restrict__ bn,
                        unsigned short* __restrict__ hb) {
    __shared__ float sx[16][68];
    int lane = threadIdx.x & 63;
    int wv = threadIdx.x >> 6;
    int m = lane & 15, quad = lane >> 4;
    int base = blockIdx.x * 16;

    const float* ap = agg + (size_t)(base + m) * D + quad * 8;
    float af[16];
    *(f32x4*)&af[0]  = *(const f32x4*)(ap);
    *(f32x4*)&af[4]  = *(const f32x4*)(ap + 4);
    *(f32x4*)&af[8]  = *(const f32x4*)(ap + 32);
    *(f32x4*)&af[12] = *(const f32x4*)(ap + 36);
    bf16x8 a0h, a0l, a1h, a1l;
#pragma unroll
    for (int j = 0; j < 8; j++) {
        short h0 = f2b(af[j]);
        short h1 = f2b(af[8 + j]);
        a0h[j] = h0; a0l[j] = f2b(af[j] - b2f((unsigned short)h0));
        a1h[j] = h1; a1l[j] = f2b(af[8 + j] - b2f((unsigned short)h1));
    }
    const unsigned short* bh = WoT_hi + ((size_t)wv * 16 + m) * 64 + quad * 8;
    const unsigned short* bl = WoT_lo + ((size_t)wv * 16 + m) * 64 + quad * 8;
    bf16x8 bh0 = *(const bf16x8*)(bh);
    bf16x8 bh1 = *(const bf16x8*)(bh + 32);
    bf16x8 bl0 = *(const bf16x8*)(bl);
    bf16x8 bl1 = *(const bf16x8*)(bl + 32);
    f32x4 c = {0.f, 0.f, 0.f, 0.f};
    c = __builtin_amdgcn_mfma_f32_16x16x32_bf16(a0h, bh0, c, 0, 0, 0);
    c = __builtin_amdgcn_mfma_f32_16x16x32_bf16(a1h, bh1, c, 0, 0, 0);
    c = __builtin_amdgcn_mfma_f32_16x16x32_bf16(a0h, bl0, c, 0, 0, 0);
    c = __builtin_amdgcn_mfma_f32_16x16x32_bf16(a1h, bl1, c, 0, 0, 0);
    c = __builtin_amdgcn_mfma_f32_16x16x32_bf16(a0l, bh0, c, 0, 0, 0);
    c = __builtin_amdgcn_mfma_f32_16x16x32_bf16(a1l, bh1, c, 0, 0, 0);

#pragma unroll
    for (int reg = 0; reg < 4; reg++) {
        int row = quad * 4 + reg;
        int col = wv * 16 + m;
        sx[row][col] = c[reg] + h[(size_t)(base + row) * D + col];
    }
    __syncthreads();

    float gcol = gn[lane], bcol = bn[lane];
#pragma unroll
    for (int it = 0; it < 4; it++) {
        int ln = wv * 4 + it;
        int node = base + ln;
        float x = sx[ln][lane];
        float sum = x, sq = x * x;
#pragma unroll
        for (int off = 32; off; off >>= 1) {
            sum += __shfl_xor(sum, off);
            sq += __shfl_xor(sq, off);
        }
        float mu = sum * (1.f / 64.f);
        float var = sq * (1.f / 64.f) - mu * mu;
        float out = (x - mu) * rsqrtf(var + 1e-5f) * gcol + bcol;
        h[(size_t)node * D + lane] = out;
        hb[(size_t)node * D + lane] = (unsigned short)f2b(out);
    }
}

// ---- e = LN(e + gelu([h[src]|h[dst]|e] @ Wem + bem)) via bf16 MFMA.
// Weights in registers, zero block barriers, 256 edges/block (64/wave).
__global__ __launch_bounds__(256, 4)
void edge_update_mfma_kernel(const unsigned short* __restrict__ hb,
                             unsigned short* __restrict__ eb_s,
                             const int2* __restrict__ es,
                             const int* __restrict__ sorted_dst,
                             const unsigned short* __restrict__ Wt,   // [32][160] bf16
                             const float* __restrict__ bem,
                             const float* __restrict__ ge,
                             const float* __restrict__ be,
                             const float* __restrict__ We_next,       // [32][4]
                             float* __restrict__ ebias_s,
                             int do_bias, int do_estore) {
    __shared__ __align__(16) float ytr[4][16][36];   // per-wave private
    int tid = threadIdx.x;
    int wave = tid >> 6;
    int lane = tid & 63;
    int wbase = blockIdx.x * 256 + wave * 64;    // 64 edges per wave
    int m = lane & 15;
    int quad = lane >> 4;

    // weight B-fragments in registers, once per wave
    const unsigned short* w0 = Wt + m * 160 + quad * 8;
    const unsigned short* w1 = Wt + (m + 16) * 160 + quad * 8;
    bf16x8 B0[5], B1[5];
#pragma unroll
    for (int ks = 0; ks < 5; ks++) {
        B0[ks] = *(const bf16x8*)(w0 + ks * 32);
        B1[ks] = *(const bf16x8*)(w1 + ks * 32);
    }
    bf16x8 wb;
#pragma unroll
    for (int j = 0; j < 8; j++) {
        float w = (do_bias && m < 4) ? We_next[(quad * 8 + j) * 4 + m] : 0.f;
        wb[j] = f2b(w);
    }
    float bm0 = bem[m], bm1 = bem[m + 16];
    float4 g0v = *(const float4*)(ge + quad * 8);
    float4 g1v = *(const float4*)(ge + quad * 8 + 4);
    float4 b0v = *(const float4*)(be + quad * 8);
    float4 b1v = *(const float4*)(be + quad * 8 + 4);
    float gg[8] = {g0v.x, g0v.y, g0v.z, g0v.w, g1v.x, g1v.y, g1v.z, g1v.w};
    float bbv[8] = {b0v.x, b0v.y, b0v.z, b0v.w, b1v.x, b1v.y, b1v.z, b1v.w};

    for (int g = 0; g < 4; g++) {
        int we = wbase + g * 16;
        int p_m = we + m;
        int s_idx = es[p_m].y, d_idx = sorted_dst[p_m];
        const unsigned short* as = hb + (size_t)s_idx * D + quad * 8;
        const unsigned short* ad = hb + (size_t)d_idx * D + quad * 8;
        bf16x8 a_s0 = *(const bf16x8*)(as);
        bf16x8 a_s1 = *(const bf16x8*)(as + 32);
        bf16x8 a_d0 = *(const bf16x8*)(ad);
        bf16x8 a_d1 = *(const bf16x8*)(ad + 32);
        bf16x8 ea = *(const bf16x8*)(eb_s + (size_t)p_m * DE + quad * 8);

        f32x4 c0 = {0.f, 0.f, 0.f, 0.f};
        f32x4 c1 = {0.f, 0.f, 0.f, 0.f};
#pragma unroll
        for (int ks = 0; ks < 4; ks++) {
            bf16x8 a = (ks == 0) ? a_s0 : (ks == 1) ? a_s1 : (ks == 2) ? a_d0 : a_d1;
            c0 = __builtin_amdgcn_mfma_f32_16x16x32_bf16(a, B0[ks], c0, 0, 0, 0);
            c1 = __builtin_amdgcn_mfma_f32_16x16x32_bf16(a, B1[ks], c1, 0, 0, 0);
        }
        c0 = __builtin_amdgcn_mfma_f32_16x16x32_bf16(ea, B0[4], c0, 0, 0, 0);
        c1 = __builtin_amdgcn_mfma_f32_16x16x32_bf16(ea, B1[4], c1, 0, 0, 0);

#pragma unroll
        for (int reg = 0; reg < 4; reg++) {
            int row = quad * 4 + reg;
            float y0 = c0[reg] + bm0;
            float y1 = c1[reg] + bm1;
            float u0 = 1.5957691216057308f * (y0 + 0.044715f * y0 * y0 * y0);
            float u1 = 1.5957691216057308f * (y1 + 0.044715f * y1 * y1 * y1);
            float t0 = 1.f - 2.f / (1.f + __expf(u0));
            float t1 = 1.f - 2.f / (1.f + __expf(u1));
            ytr[wave][row][m] = 0.5f * y0 * (1.f + t0);
            ytr[wave][row][m + 16] = 0.5f * y1 * (1.f + t1);
        }
        // same-wave LDS write->read: DS pipe is in-order per wave, no barrier

        float y[8];
        *(f32x4*)&y[0] = *(const f32x4*)&ytr[wave][m][quad * 8];
        *(f32x4*)&y[4] = *(const f32x4*)&ytr[wave][m][quad * 8 + 4];
        float s = 0.f, sq = 0.f;
#pragma unroll
        for (int j = 0; j < 8; j++) {
            y[j] += b2f((unsigned short)ea[j]);      // residual (from A-frag)
            s += y[j];
            sq += y[j] * y[j];
        }
        s += __shfl_xor(s, 16); s += __shfl_xor(s, 32);
        sq += __shfl_xor(sq, 16); sq += __shfl_xor(sq, 32);
        float mu = s * (1.f / 32.f);
        float var = sq * (1.f / 32.f) - mu * mu;
        float inv = rsqrtf(var + 1e-5f);

        bf16x8 zb;
#pragma unroll
        for (int j = 0; j < 8; j++) {
            float z = (y[j] - mu) * inv * gg[j] + bbv[j];
            zb[j] = f2b(z);
        }
        if (do_estore) {
            *(s16x8*)(eb_s + (size_t)p_m * DE + quad * 8) = zb;
        }
        if (do_bias) {
            f32x4 db = {0.f, 0.f, 0.f, 0.f};
            db = __builtin_amdgcn_mfma_f32_16x16x32_bf16(zb, wb, db, 0, 0, 0);
            if (m < 4) {
#pragma unroll
                for (int reg = 0; reg < 4; reg++) {
                    ebias_s[(we + quad * 4 + reg) * H + m] = db[reg];
                }
            }
        }
    }
}

extern "C" void kernel_launch(void* const* d_in, const int* in_sizes, int n_in,
                              void* d_out, int out_size, void* d_ws, size_t ws_size,
                              hipStream_t stream) {
    const float* node_features = (const float*)d_in[0];
    const float* e = (const float*)d_in[1];   // pristine fp32 e (read-only)
    const int* edge_index = (const int*)d_in[2];
    const int* src = edge_index;
    const int* dst = edge_index + NE;
    const float* Wq = (const float*)d_in[3];
    const float* Wk = (const float*)d_in[4];
    const float* Wv = (const float*)d_in[5];
    const float* Wo = (const float*)d_in[6];
    const float* We = (const float*)d_in[7];
    const float* Wem = (const float*)d_in[8];
    const float* bem = (const float*)d_in[9];
    const float* gn = (const float*)d_in[10];
    const float* bn = (const float*)d_in[11];
    const float* ge = (const float*)d_in[12];
    const float* be = (const float*)d_in[13];

    float* h = (float*)d_out;       // h lives in d_out

    float* ws = (float*)d_ws;
    float* q = ws;                                       // N*D f32
    unsigned int* kv = (unsigned int*)(q + NN * D);      // N*D u32 (packed bf16 k|v)
    float* agg = (float*)(kv + NN * D);                  // N*D f32
    float* ebias_s = agg + NN * D;                       // E*H f32 (sorted order)
    int* offsets = (int*)(ebias_s + (size_t)NE * H);     // NN
    int* cursor = offsets + NN;                          // NN
    int* bsum = cursor + NN;                             // 64
    int2* sorted_es = (int2*)(bsum + 64);                // NE int2 {eid, src}
    int* sorted_dst = (int*)(sorted_es + NE);            // NE
    unsigned short* Wt = (unsigned short*)(sorted_dst + NE);  // L*32*160 bf16
    unsigned short* hb = Wt + L * 32 * 160;              // N*D bf16
    unsigned short* eb_s = hb + NN * D;                  // E*DE bf16 e-state (sorted)
    unsigned short* WT_hi = eb_s + (size_t)NE * DE;      // L*4*64*64 bf16
    unsigned short* WT_lo = WT_hi + L * 4 * 64 * 64;     // L*4*64*64 bf16

    const int NB = (NN + 1023) / 1024;

    // ---- CSR build + preconverts (inputs constant; rebuilt every launch) ----
    hipMemsetAsync(cursor, 0, NN * sizeof(int), stream);
    deg_kernel<<<(NE + 255) / 256, 256, 0, stream>>>(dst, cursor);
    block_sum_kernel<<<NB, 256, 0, stream>>>(cursor, bsum);
    scan_bsum_kernel<<<1, 64, 0, stream>>>(bsum, NB);
    scan_block_kernel<<<NB, 256, 0, stream>>>(cursor, bsum, offsets);
    scatter_kernel<<<(NE + 255) / 256, 256, 0, stream>>>(src, dst, cursor, sorted_es);
    fill_dst_kernel<<<(NN + 255) / 256, 256, 0, stream>>>(offsets, sorted_dst);
    eperm_kernel<<<(NE * 4 + 255) / 256, 256, 0, stream>>>(e, sorted_es, We, eb_s, ebias_s);
    wconv_kernel<<<(L * 32 * 160 + 255) / 256, 256, 0, stream>>>(Wem, Wt);
    wsplit_kernel<<<(L * 4 * 64 * 64 + 255) / 256, 256, 0, stream>>>(Wq, Wk, Wv, Wo,
                                                                     WT_hi, WT_lo);
    hconv_kernel<<<(NN * D + 255) / 256, 256, 0, stream>>>(node_features, h, hb);

    for (int layer = 0; layer < L; layer++) {
        const unsigned short* WT_hi_l = WT_hi + (size_t)layer * 4 * 4096;
        const unsigned short* WT_lo_l = WT_lo + (size_t)layer * 4 * 4096;
        const unsigned short* Wt_l = Wt + layer * 32 * 160;
        const float* bem_l = bem + layer * DE;
        const float* gn_l = gn + layer * D;
        const float* bn_l = bn + layer * D;
        const float* ge_l = ge + layer * DE;
        const float* be_l = be + layer * DE;

        qkv_kernel<<<NN / 16, 256, 0, stream>>>(h, WT_hi_l, WT_lo_l, q, kv);
        attn_kernel<<<NN / 4, dim3(64, 4), 0, stream>>>(q, kv, ebias_s, sorted_es,
                                                        offsets, agg);
        node_update_kernel<<<NN / 16, 256, 0, stream>>>(h, agg,
                                                        WT_hi_l + 3 * 4096,
                                                        WT_lo_l + 3 * 4096,
                                                        gn_l, bn_l, hb);
        // layer 0: full edge update; layer 1: bias-only; layer 2: skipped
        if (layer < L - 1) {
            const float* We_next = We + (layer + 1) * DE * H;
            edge_update_mfma_kernel<<<NE / 256, 256, 0, stream>>>(hb, eb_s, sorted_es,
                                                                  sorted_dst, Wt_l,
                                                                  bem_l, ge_l, be_l,
                                                                  We_next, ebias_s,
                                                                  1, layer == 0 ? 1 : 0);
        }
    }
}

// Round 7
// 1078.136 us; speedup vs baseline: 1.0532x; 1.0319x over previous
//
#include <hip/hip_runtime.h>
#include <hip/hip_bf16.h>
#include <math.h>

#define NN 50000
#define NE 1600000
#define D 64
#define DE 32
#define H 4
#define DH 16
#define L 3
#define BKT_SHIFT 10
#define NBKT 49    // ceil(50000/1024)

typedef __attribute__((ext_vector_type(8))) short bf16x8;
typedef __attribute__((ext_vector_type(8))) short s16x8;
typedef __attribute__((ext_vector_type(4))) float f32x4;
typedef __attribute__((ext_vector_type(4))) unsigned int u32x4;

__device__ __forceinline__ short f2b(float f) {
    __hip_bfloat16 h = __float2bfloat16(f);
    short s;
    __builtin_memcpy(&s, &h, 2);
    return s;
}
__device__ __forceinline__ float b2f(unsigned short u) {
    unsigned int x = ((unsigned int)u) << 16;
    float f; __builtin_memcpy(&f, &x, 4); return f;
}
__device__ __forceinline__ float b2f_lo(unsigned int p) {
    unsigned int x = p << 16;
    float f; __builtin_memcpy(&f, &x, 4); return f;
}
__device__ __forceinline__ float b2f_hi(unsigned int p) {
    unsigned int x = p & 0xffff0000u;
    float f; __builtin_memcpy(&f, &x, 4); return f;
}

// ======================= CSR build (per launch) =======================

__global__ void deg_kernel(const int* __restrict__ dst, int* __restrict__ cnt) {
    int e = blockIdx.x * 256 + threadIdx.x;
    if (e >= NE) return;
    atomicAdd(&cnt[dst[e]], 1);
}

__global__ void block_sum_kernel(const int* __restrict__ cnt, int* __restrict__ bsum) {
    int b = blockIdx.x, t = threadIdx.x;
    int base = b * 1024 + t * 4;
    int s = 0;
#pragma unroll
    for (int i = 0; i < 4; i++) { int idx = base + i; if (idx < NN) s += cnt[idx]; }
#pragma unroll
    for (int off = 32; off; off >>= 1) s += __shfl_down(s, off);
    __shared__ int wsum[4];
    if ((t & 63) == 0) wsum[t >> 6] = s;
    __syncthreads();
    if (t == 0) bsum[b] = wsum[0] + wsum[1] + wsum[2] + wsum[3];
}

// one-wave exclusive prefix scan over nb (<=64) block sums
__global__ void scan_bsum_kernel(int* __restrict__ bsum, int nb) {
    int t = threadIdx.x;    // 64 threads
    int v = (t < nb) ? bsum[t] : 0;
    int x = v;
#pragma unroll
    for (int off = 1; off < 64; off <<= 1) {
        int y = __shfl_up(x, off);
        if (t >= off) x += y;
    }
    if (t < nb) bsum[t] = x - v;
}

__global__ void scan_block_kernel(const int* __restrict__ cnt, const int* __restrict__ bsum,
                                  int* __restrict__ offsets) {
    int b = blockIdx.x, t = threadIdx.x;
    int base = b * 1024 + t * 4;
    int v[4]; int s = 0;
#pragma unroll
    for (int i = 0; i < 4; i++) { int idx = base + i; v[i] = (idx < NN) ? cnt[idx] : 0; s += v[i]; }
    int lane = t & 63, w = t >> 6;
    int x = s;
#pragma unroll
    for (int off = 1; off < 64; off <<= 1) {
        int y = __shfl_up(x, off);
        if (lane >= off) x += y;
    }
    __shared__ int wsum[4];
    if (lane == 63) wsum[w] = x;
    __syncthreads();
    int woff = 0;
    for (int i = 0; i < w; i++) woff += wsum[i];
    int run = bsum[b] + woff + x - s;
#pragma unroll
    for (int i = 0; i < 4; i++) {
        int idx = base + i;
        if (idx < NN) offsets[idx] = run;
        run += v[i];
    }
}

__global__ void init_bkt_kernel(const int* __restrict__ offsets, int* __restrict__ bucket_cursor) {
    int t = threadIdx.x;   // 64
    if (t < NBKT) bucket_cursor[t] = offsets[t << BKT_SHIFT];
}

// ---- two-pass binned scatter: pass B groups edges by 1024-node bucket
// (LDS histogram, sequential-run writes → full lines) ----
__global__ __launch_bounds__(256)
void bin_kernel(const int* __restrict__ src, const int* __restrict__ dst,
                int* __restrict__ bucket_cursor, int4* __restrict__ binned) {
    __shared__ int hist[64], base[64];
    int tid = threadIdx.x;
    if (tid < 64) hist[tid] = 0;
    __syncthreads();
    int e0 = blockIdx.x * 1024;
    int ee[4], s4[4], d4[4], bk[4], rk[4];
#pragma unroll
    for (int i = 0; i < 4; i++) {
        int e = e0 + tid + i * 256;
        ee[i] = e;
        bool v = e < NE;
        d4[i] = v ? dst[e] : 0;
        s4[i] = v ? src[e] : 0;
        bk[i] = d4[i] >> BKT_SHIFT;
        rk[i] = v ? atomicAdd(&hist[bk[i]], 1) : 0;
    }
    __syncthreads();
    if (tid < 64) base[tid] = hist[tid] ? atomicAdd(&bucket_cursor[tid], hist[tid]) : 0;
    __syncthreads();
#pragma unroll
    for (int i = 0; i < 4; i++) {
        if (ee[i] < NE) {
            int4 v; v.x = ee[i]; v.y = s4[i]; v.z = d4[i]; v.w = 0;
            binned[base[bk[i]] + rk[i]] = v;
        }
    }
}

// ---- pass C: one block per bucket; per-node cursors in LDS; all writes
// land in this block's ~800KB window → full lines assembled in one L2 ----
__global__ __launch_bounds__(1024)
void fine_scatter_kernel(const int4* __restrict__ binned, const int* __restrict__ offsets,
                         int2* __restrict__ sorted_es, int* __restrict__ sorted_dst) {
    __shared__ int cur[1024];
    int b = blockIdx.x;
    int nbase = b << BKT_SHIFT;
    int tid = threadIdx.x;
    int nid = nbase + tid;
    cur[tid] = (nid < NN) ? offsets[nid] : 0;
    int beg = offsets[nbase];
    int nend = nbase + 1024;
    int end = (nend >= NN) ? NE : offsets[nend];
    __syncthreads();
    for (int i = beg + tid; i < end; i += 1024) {
        int4 v = binned[i];
        int pos = atomicAdd(&cur[v.z - nbase], 1);
        int2 es; es.x = v.x; es.y = v.y;
        sorted_es[pos] = es;
        sorted_dst[pos] = v.z;
    }
}

// ---- permute pristine fp32 e into dst-sorted bf16 eb_s + fused layer-0
// edge bias (from the pristine fp32 values). Only compulsory traffic. ----
__global__ void eperm_kernel(const float* __restrict__ e32, const int2* __restrict__ sorted_es,
                             const float* __restrict__ We0,
                             unsigned short* __restrict__ eb_s,
                             float* __restrict__ ebias_s) {
    int t = blockIdx.x * 256 + threadIdx.x;
    if (t >= NE * 4) return;
    int p = t >> 2;
    int c = (t & 3) * 8;
    int eid = sorted_es[p].x;
    const float* ep = e32 + (size_t)eid * DE + c;
    float4 x0 = *(const float4*)(ep);
    float4 x1 = *(const float4*)(ep + 4);
    float e8[8] = {x0.x, x0.y, x0.z, x0.w, x1.x, x1.y, x1.z, x1.w};
    s16x8 ob;
#pragma unroll
    for (int i = 0; i < 8; i++) ob[i] = f2b(e8[i]);
    *(s16x8*)(eb_s + (size_t)p * DE + c) = ob;
    float p0 = 0.f, p1 = 0.f, p2 = 0.f, p3 = 0.f;
#pragma unroll
    for (int i = 0; i < 8; i++) {
        float4 w = *(const float4*)(We0 + (c + i) * 4);
        p0 += e8[i] * w.x; p1 += e8[i] * w.y; p2 += e8[i] * w.z; p3 += e8[i] * w.w;
    }
#pragma unroll
    for (int off = 1; off < 4; off <<= 1) {
        p0 += __shfl_xor(p0, off, 4);
        p1 += __shfl_xor(p1, off, 4);
        p2 += __shfl_xor(p2, off, 4);
        p3 += __shfl_xor(p3, off, 4);
    }
    if ((t & 3) == 0) {
        float4 o; o.x = p0; o.y = p1; o.z = p2; o.w = p3;
        *(float4*)(ebias_s + (size_t)p * H) = o;
    }
}

// ---- Wem[L][160][32] fp32 -> Wt[L][32][160] bf16 (transposed) ----
__global__ void wconv_kernel(const float* __restrict__ Wem, unsigned short* __restrict__ Wt) {
    int t = blockIdx.x * 256 + threadIdx.x;
    if (t >= L * 32 * 160) return;
    int l = t / 5120;
    int r = t % 5120;
    int n = r / 160;
    int k = r % 160;
    Wt[t] = (unsigned short)f2b(Wem[l * 5120 + k * 32 + n]);
}

// ---- Wq/Wk/Wv/Wo -> transposed bf16 hi/lo split: WT[l][mat][n][k] ----
__global__ void wsplit_kernel(const float* __restrict__ Wq, const float* __restrict__ Wk,
                              const float* __restrict__ Wv, const float* __restrict__ Wo,
                              unsigned short* __restrict__ WT_hi,
                              unsigned short* __restrict__ WT_lo) {
    int t = blockIdx.x * 256 + threadIdx.x;
    if (t >= L * 4 * 64 * 64) return;
    int k = t & 63;
    int n = (t >> 6) & 63;
    int mat = (t >> 12) & 3;
    int l = t >> 14;
    const float* W = (mat == 0) ? Wq : (mat == 1) ? Wk : (mat == 2) ? Wv : Wo;
    float w = W[l * 4096 + k * 64 + n];
    unsigned short hi = (unsigned short)f2b(w);
    float lo = w - b2f(hi);
    WT_hi[t] = hi;
    WT_lo[t] = (unsigned short)f2b(lo);
}

// ---- h = node_features (fp32) + hb = bf16(node_features) ----
__global__ void hconv_kernel(const float* __restrict__ nf, float* __restrict__ h,
                             unsigned short* __restrict__ hb) {
    int t = blockIdx.x * 256 + threadIdx.x;
    if (t >= NN * D) return;
    float x = nf[t];
    h[t] = x;
    hb[t] = (unsigned short)f2b(x);
}

// ======================= per-layer kernels =======================

// ---- q = (h@Wq)*0.25 ; kv = pack(bf16(k), bf16(v)) via bf16x3 MFMA ----
__global__ __launch_bounds__(256, 8)
void qkv_kernel(const float* __restrict__ h,
                const unsigned short* __restrict__ WT_hi,   // this layer: [4][64][64]
                const unsigned short* __restrict__ WT_lo,
                float* __restrict__ q, unsigned int* __restrict__ kv) {
    int lane = threadIdx.x & 63;
    int wv = threadIdx.x >> 6;
    int m = lane & 15, quad = lane >> 4;
    int base = blockIdx.x * 16;

    const float* hp = h + (size_t)(base + m) * D + quad * 8;
    float af[16];
    *(f32x4*)&af[0]  = *(const f32x4*)(hp);
    *(f32x4*)&af[4]  = *(const f32x4*)(hp + 4);
    *(f32x4*)&af[8]  = *(const f32x4*)(hp + 32);
    *(f32x4*)&af[12] = *(const f32x4*)(hp + 36);
    bf16x8 a0h, a0l, a1h, a1l;
#pragma unroll
    for (int j = 0; j < 8; j++) {
        short h0 = f2b(af[j]);
        short h1 = f2b(af[8 + j]);
        a0h[j] = h0; a0l[j] = f2b(af[j] - b2f((unsigned short)h0));
        a1h[j] = h1; a1l[j] = f2b(af[8 + j] - b2f((unsigned short)h1));
    }

    f32x4 acc[3];
#pragma unroll
    for (int mat = 0; mat < 3; mat++) {
        const unsigned short* bh = WT_hi + ((size_t)mat * 64 + wv * 16 + m) * 64 + quad * 8;
        const unsigned short* bl = WT_lo + ((size_t)mat * 64 + wv * 16 + m) * 64 + quad * 8;
        bf16x8 bh0 = *(const bf16x8*)(bh);
        bf16x8 bh1 = *(const bf16x8*)(bh + 32);
        bf16x8 bl0 = *(const bf16x8*)(bl);
        bf16x8 bl1 = *(const bf16x8*)(bl + 32);
        f32x4 c = {0.f, 0.f, 0.f, 0.f};
        c = __builtin_amdgcn_mfma_f32_16x16x32_bf16(a0h, bh0, c, 0, 0, 0);
        c = __builtin_amdgcn_mfma_f32_16x16x32_bf16(a1h, bh1, c, 0, 0, 0);
        c = __builtin_amdgcn_mfma_f32_16x16x32_bf16(a0h, bl0, c, 0, 0, 0);
        c = __builtin_amdgcn_mfma_f32_16x16x32_bf16(a1h, bl1, c, 0, 0, 0);
        c = __builtin_amdgcn_mfma_f32_16x16x32_bf16(a0l, bh0, c, 0, 0, 0);
        c = __builtin_amdgcn_mfma_f32_16x16x32_bf16(a1l, bh1, c, 0, 0, 0);
        acc[mat] = c;
    }

#pragma unroll
    for (int reg = 0; reg < 4; reg++) {
        int row = base + quad * 4 + reg;
        int col = wv * 16 + m;
        q[(size_t)row * D + col] = acc[0][reg] * 0.25f;
        unsigned int kb = (unsigned short)f2b(acc[1][reg]);
        unsigned int vb = (unsigned short)f2b(acc[2][reg]);
        kv[(size_t)row * D + col] = (vb << 16) | kb;
    }
}

// ---- attention: lane = (edge u, head h). Full 16-dim dot in registers;
// exp without max-subtraction (shift-invariant; LN'd inputs keep |score| small).
__global__ __launch_bounds__(256, 8)
void attn_kernel(const float* __restrict__ q, const unsigned int* __restrict__ kv,
                 const float* __restrict__ ebias_s,
                 const int2* __restrict__ es,
                 const int* __restrict__ offsets,
                 float* __restrict__ agg) {
    __shared__ __align__(16) float sacc[4][4][16][20];   // [wave][head][u][j], pad 20
    int wave = threadIdx.y;
    int node = blockIdx.x * 4 + wave;
    node = __builtin_amdgcn_readfirstlane(node);
    if (node >= NN) return;
    int lane = threadIdx.x;
    int u = lane & 15, hh = lane >> 4;

    float qv[16];
    const float* qp = q + (size_t)node * D + hh * 16;
    *(f32x4*)&qv[0]  = *(const f32x4*)(qp);
    *(f32x4*)&qv[4]  = *(const f32x4*)(qp + 4);
    *(f32x4*)&qv[8]  = *(const f32x4*)(qp + 8);
    *(f32x4*)&qv[12] = *(const f32x4*)(qp + 12);

    int beg = offsets[node];
    int end = (node == NN - 1) ? NE : offsets[node + 1];
    float den = 0.f;
    float acc[16];
#pragma unroll
    for (int j = 0; j < 16; j++) acc[j] = 0.f;

    for (int i = beg; i < end; i += 16) {
        int idx = i + u;
        bool valid = idx < end;
        int sidx = valid ? idx : (end - 1);
        int s = es[sidx].y;
        float bias = ebias_s[sidx * H + hh];
        const unsigned int* kp = kv + (size_t)s * D + hh * 16;
        unsigned int kr[16];
        *(u32x4*)&kr[0]  = *(const u32x4*)(kp);
        *(u32x4*)&kr[4]  = *(const u32x4*)(kp + 4);
        *(u32x4*)&kr[8]  = *(const u32x4*)(kp + 8);
        *(u32x4*)&kr[12] = *(const u32x4*)(kp + 12);
        float dot = bias;
#pragma unroll
        for (int j = 0; j < 16; j++) dot += qv[j] * b2f_lo(kr[j]);
        float p = valid ? __expf(dot) : 0.f;
        den += p;
#pragma unroll
        for (int j = 0; j < 16; j++) acc[j] += p * b2f_hi(kr[j]);
    }

    // merge across the 16 lanes of this head group
    *(f32x4*)&sacc[wave][hh][u][0]  = *(const f32x4*)&acc[0];
    *(f32x4*)&sacc[wave][hh][u][4]  = *(const f32x4*)&acc[4];
    *(f32x4*)&sacc[wave][hh][u][8]  = *(const f32x4*)&acc[8];
    *(f32x4*)&sacc[wave][hh][u][12] = *(const f32x4*)&acc[12];
#pragma unroll
    for (int off = 1; off < 16; off <<= 1) den += __shfl_xor(den, off, 16);
    float o = 0.f;
#pragma unroll
    for (int u2 = 0; u2 < 16; u2++) o += sacc[wave][hh][u2][u];
    agg[(size_t)node * D + hh * 16 + u] = o / (den + 1e-9f);
}

// ---- h = LN(h + agg @ Wo) + bf16 shadow ; agg@Wo via bf16x3 MFMA ----
__global__ __launch_bounds__(256, 8)
void node_update_kernel(float* __restrict__ h, const float* __restrict__ agg,
                        const unsigned short* __restrict__ WoT_hi,   // [64][64]
                        const unsigned short* __restrict__ WoT_lo,
                        const float* __restrict__ gn,
                        const float* __restrict__ bn,
                        unsigned short* __restrict__ hb) {
    __shared__ float sx[16][68];
    int lane = threadIdx.x & 63;
    int wv = threadIdx.x >> 6;
    int m = lane & 15, quad = lane >> 4;
    int base = blockIdx.x * 16;

    const float* ap = agg + (size_t)(base + m) * D + quad * 8;
    float af[16];
    *(f32x4*)&af[0]  = *(const f32x4*)(ap);
    *(f32x4*)&af[4]  = *(const f32x4*)(ap + 4);
    *(f32x4*)&af[8]  = *(const f32x4*)(ap + 32);
    *(f32x4*)&af[12] = *(const f32x4*)(ap + 36);
    bf16x8 a0h, a0l, a1h, a1l;
#pragma unroll
    for (int j = 0; j < 8; j++) {
        short h0 = f2b(af[j]);
        short h1 = f2b(af[8 + j]);
        a0h[j] = h0; a0l[j] = f2b(af[j] - b2f((unsigned short)h0));
        a1h[j] = h1; a1l[j] = f2b(af[8 + j] - b2f((unsigned short)h1));
    }
    const unsigned short* bh = WoT_hi + ((size_t)wv * 16 + m) * 64 + quad * 8;
    const unsigned short* bl = WoT_lo + ((size_t)wv * 16 + m) * 64 + quad * 8;
    bf16x8 bh0 = *(const bf16x8*)(bh);
    bf16x8 bh1 = *(const bf16x8*)(bh + 32);
    bf16x8 bl0 = *(const bf16x8*)(bl);
    bf16x8 bl1 = *(const bf16x8*)(bl + 32);
    f32x4 c = {0.f, 0.f, 0.f, 0.f};
    c = __builtin_amdgcn_mfma_f32_16x16x32_bf16(a0h, bh0, c, 0, 0, 0);
    c = __builtin_amdgcn_mfma_f32_16x16x32_bf16(a1h, bh1, c, 0, 0, 0);
    c = __builtin_amdgcn_mfma_f32_16x16x32_bf16(a0h, bl0, c, 0, 0, 0);
    c = __builtin_amdgcn_mfma_f32_16x16x32_bf16(a1h, bl1, c, 0, 0, 0);
    c = __builtin_amdgcn_mfma_f32_16x16x32_bf16(a0l, bh0, c, 0, 0, 0);
    c = __builtin_amdgcn_mfma_f32_16x16x32_bf16(a1l, bh1, c, 0, 0, 0);

#pragma unroll
    for (int reg = 0; reg < 4; reg++) {
        int row = quad * 4 + reg;
        int col = wv * 16 + m;
        sx[row][col] = c[reg] + h[(size_t)(base + row) * D + col];
    }
    __syncthreads();

    float gcol = gn[lane], bcol = bn[lane];
#pragma unroll
    for (int it = 0; it < 4; it++) {
        int ln = wv * 4 + it;
        int node = base + ln;
        float x = sx[ln][lane];
        float sum = x, sq = x * x;
#pragma unroll
        for (int off = 32; off; off >>= 1) {
            sum += __shfl_xor(sum, off);
            sq += __shfl_xor(sq, off);
        }
        float mu = sum * (1.f / 64.f);
        float var = sq * (1.f / 64.f) - mu * mu;
        float out = (x - mu) * rsqrtf(var + 1e-5f) * gcol + bcol;
        h[(size_t)node * D + lane] = out;
        hb[(size_t)node * D + lane] = (unsigned short)f2b(out);
    }
}

// ---- e = LN(e + gelu([h[src]|h[dst]|e] @ Wem + bem)) via bf16 MFMA.
// Weights in registers, zero block barriers, 256 edges/block (64/wave).
__global__ __launch_bounds__(256, 4)
void edge_update_mfma_kernel(const unsigned short* __restrict__ hb,
                             unsigned short* __restrict__ eb_s,
                             const int2* __restrict__ es,
                             const int* __restrict__ sorted_dst,
                             const unsigned short* __restrict__ Wt,   // [32][160] bf16
                             const float* __restrict__ bem,
                             const float* __restrict__ ge,
                             const float* __restrict__ be,
                             const float* __restrict__ We_next,       // [32][4]
                             float* __restrict__ ebias_s,
                             int do_bias, int do_estore) {
    __shared__ __align__(16) float ytr[4][16][36];   // per-wave private
    int tid = threadIdx.x;
    int wave = tid >> 6;
    int lane = tid & 63;
    int wbase = blockIdx.x * 256 + wave * 64;    // 64 edges per wave
    int m = lane & 15;
    int quad = lane >> 4;

    // weight B-fragments in registers, once per wave
    const unsigned short* w0 = Wt + m * 160 + quad * 8;
    const unsigned short* w1 = Wt + (m + 16) * 160 + quad * 8;
    bf16x8 B0[5], B1[5];
#pragma unroll
    for (int ks = 0; ks < 5; ks++) {
        B0[ks] = *(const bf16x8*)(w0 + ks * 32);
        B1[ks] = *(const bf16x8*)(w1 + ks * 32);
    }
    bf16x8 wb;
#pragma unroll
    for (int j = 0; j < 8; j++) {
        float w = (do_bias && m < 4) ? We_next[(quad * 8 + j) * 4 + m] : 0.f;
        wb[j] = f2b(w);
    }
    float bm0 = bem[m], bm1 = bem[m + 16];
    float4 g0v = *(const float4*)(ge + quad * 8);
    float4 g1v = *(const float4*)(ge + quad * 8 + 4);
    float4 b0v = *(const float4*)(be + quad * 8);
    float4 b1v = *(const float4*)(be + quad * 8 + 4);
    float gg[8] = {g0v.x, g0v.y, g0v.z, g0v.w, g1v.x, g1v.y, g1v.z, g1v.w};
    float bbv[8] = {b0v.x, b0v.y, b0v.z, b0v.w, b1v.x, b1v.y, b1v.z, b1v.w};

    for (int g = 0; g < 4; g++) {
        int we = wbase + g * 16;
        int p_m = we + m;
        int s_idx = es[p_m].y, d_idx = sorted_dst[p_m];
        const unsigned short* as = hb + (size_t)s_idx * D + quad * 8;
        const unsigned short* ad = hb + (size_t)d_idx * D + quad * 8;
        bf16x8 a_s0 = *(const bf16x8*)(as);
        bf16x8 a_s1 = *(const bf16x8*)(as + 32);
        bf16x8 a_d0 = *(const bf16x8*)(ad);
        bf16x8 a_d1 = *(const bf16x8*)(ad + 32);
        bf16x8 ea = *(const bf16x8*)(eb_s + (size_t)p_m * DE + quad * 8);

        f32x4 c0 = {0.f, 0.f, 0.f, 0.f};
        f32x4 c1 = {0.f, 0.f, 0.f, 0.f};
#pragma unroll
        for (int ks = 0; ks < 4; ks++) {
            bf16x8 a = (ks == 0) ? a_s0 : (ks == 1) ? a_s1 : (ks == 2) ? a_d0 : a_d1;
            c0 = __builtin_amdgcn_mfma_f32_16x16x32_bf16(a, B0[ks], c0, 0, 0, 0);
            c1 = __builtin_amdgcn_mfma_f32_16x16x32_bf16(a, B1[ks], c1, 0, 0, 0);
        }
        c0 = __builtin_amdgcn_mfma_f32_16x16x32_bf16(ea, B0[4], c0, 0, 0, 0);
        c1 = __builtin_amdgcn_mfma_f32_16x16x32_bf16(ea, B1[4], c1, 0, 0, 0);

#pragma unroll
        for (int reg = 0; reg < 4; reg++) {
            int row = quad * 4 + reg;
            float y0 = c0[reg] + bm0;
            float y1 = c1[reg] + bm1;
            float u0 = 1.5957691216057308f * (y0 + 0.044715f * y0 * y0 * y0);
            float u1 = 1.5957691216057308f * (y1 + 0.044715f * y1 * y1 * y1);
            float t0 = 1.f - 2.f / (1.f + __expf(u0));
            float t1 = 1.f - 2.f / (1.f + __expf(u1));
            ytr[wave][row][m] = 0.5f * y0 * (1.f + t0);
            ytr[wave][row][m + 16] = 0.5f * y1 * (1.f + t1);
        }
        // same-wave LDS write->read: DS pipe is in-order per wave, no barrier

        float y[8];
        *(f32x4*)&y[0] = *(const f32x4*)&ytr[wave][m][quad * 8];
        *(f32x4*)&y[4] = *(const f32x4*)&ytr[wave][m][quad * 8 + 4];
        float s = 0.f, sq = 0.f;
#pragma unroll
        for (int j = 0; j < 8; j++) {
            y[j] += b2f((unsigned short)ea[j]);      // residual (from A-frag)
            s += y[j];
            sq += y[j] * y[j];
        }
        s += __shfl_xor(s, 16); s += __shfl_xor(s, 32);
        sq += __shfl_xor(sq, 16); sq += __shfl_xor(sq, 32);
        float mu = s * (1.f / 32.f);
        float var = sq * (1.f / 32.f) - mu * mu;
        float inv = rsqrtf(var + 1e-5f);

        bf16x8 zb;
#pragma unroll
        for (int j = 0; j < 8; j++) {
            float z = (y[j] - mu) * inv * gg[j] + bbv[j];
            zb[j] = f2b(z);
        }
        if (do_estore) {
            *(s16x8*)(eb_s + (size_t)p_m * DE + quad * 8) = zb;
        }
        if (do_bias) {
            f32x4 db = {0.f, 0.f, 0.f, 0.f};
            db = __builtin_amdgcn_mfma_f32_16x16x32_bf16(zb, wb, db, 0, 0, 0);
            if (m < 4) {
#pragma unroll
                for (int reg = 0; reg < 4; reg++) {
                    ebias_s[(we + quad * 4 + reg) * H + m] = db[reg];
                }
            }
        }
    }
}

extern "C" void kernel_launch(void* const* d_in, const int* in_sizes, int n_in,
                              void* d_out, int out_size, void* d_ws, size_t ws_size,
                              hipStream_t stream) {
    const float* node_features = (const float*)d_in[0];
    const float* e = (const float*)d_in[1];   // pristine fp32 e (read-only)
    const int* edge_index = (const int*)d_in[2];
    const int* src = edge_index;
    const int* dst = edge_index + NE;
    const float* Wq = (const float*)d_in[3];
    const float* Wk = (const float*)d_in[4];
    const float* Wv = (const float*)d_in[5];
    const float* Wo = (const float*)d_in[6];
    const float* We = (const float*)d_in[7];
    const float* Wem = (const float*)d_in[8];
    const float* bem = (const float*)d_in[9];
    const float* gn = (const float*)d_in[10];
    const float* bn = (const float*)d_in[11];
    const float* ge = (const float*)d_in[12];
    const float* be = (const float*)d_in[13];

    float* h = (float*)d_out;       // h lives in d_out

    float* ws = (float*)d_ws;
    float* q = ws;                                       // N*D f32
    unsigned int* kv = (unsigned int*)(q + NN * D);      // N*D u32 (packed bf16 k|v)
    float* agg = (float*)(kv + NN * D);                  // N*D f32
    float* ebias_s = agg + NN * D;                       // E*H f32 (sorted order)
    int* offsets = (int*)(ebias_s + (size_t)NE * H);     // NN
    int* cursor = offsets + NN;                          // NN (deg counts)
    int* bsum = cursor + NN;                             // 64
    int* bucket_cursor = bsum + 64;                      // 64
    int2* sorted_es = (int2*)(bucket_cursor + 64);       // NE int2 {eid, src}
    int* sorted_dst = (int*)(sorted_es + NE);            // NE
    int4* binned = (int4*)(sorted_dst + NE);             // NE int4 {eid,src,dst,0}
    unsigned short* Wt = (unsigned short*)(binned + NE); // L*32*160 bf16
    unsigned short* hb = Wt + L * 32 * 160;              // N*D bf16
    unsigned short* eb_s = hb + NN * D;                  // E*DE bf16 e-state (sorted)
    unsigned short* WT_hi = eb_s + (size_t)NE * DE;      // L*4*64*64 bf16
    unsigned short* WT_lo = WT_hi + L * 4 * 64 * 64;     // L*4*64*64 bf16

    const int NB = (NN + 1023) / 1024;

    // ---- CSR build + preconverts (inputs constant; rebuilt every launch) ----
    hipMemsetAsync(cursor, 0, NN * sizeof(int), stream);
    deg_kernel<<<(NE + 255) / 256, 256, 0, stream>>>(dst, cursor);
    block_sum_kernel<<<NB, 256, 0, stream>>>(cursor, bsum);
    scan_bsum_kernel<<<1, 64, 0, stream>>>(bsum, NB);
    scan_block_kernel<<<NB, 256, 0, stream>>>(cursor, bsum, offsets);
    init_bkt_kernel<<<1, 64, 0, stream>>>(offsets, bucket_cursor);
    bin_kernel<<<(NE + 1023) / 1024, 256, 0, stream>>>(src, dst, bucket_cursor, binned);
    fine_scatter_kernel<<<NBKT, 1024, 0, stream>>>(binned, offsets, sorted_es, sorted_dst);
    eperm_kernel<<<(NE * 4 + 255) / 256, 256, 0, stream>>>(e, sorted_es, We, eb_s, ebias_s);
    wconv_kernel<<<(L * 32 * 160 + 255) / 256, 256, 0, stream>>>(Wem, Wt);
    wsplit_kernel<<<(L * 4 * 64 * 64 + 255) / 256, 256, 0, stream>>>(Wq, Wk, Wv, Wo,
                                                                     WT_hi, WT_lo);
    hconv_kernel<<<(NN * D + 255) / 256, 256, 0, stream>>>(node_features, h, hb);

    for (int layer = 0; layer < L; layer++) {
        const unsigned short* WT_hi_l = WT_hi + (size_t)layer * 4 * 4096;
        const unsigned short* WT_lo_l = WT_lo + (size_t)layer * 4 * 4096;
        const unsigned short* Wt_l = Wt + layer * 32 * 160;
        const float* bem_l = bem + layer * DE;
        const float* gn_l = gn + layer * D;
        const float* bn_l = bn + layer * D;
        const float* ge_l = ge + layer * DE;
        const float* be_l = be + layer * DE;

        qkv_kernel<<<NN / 16, 256, 0, stream>>>(h, WT_hi_l, WT_lo_l, q, kv);
        attn_kernel<<<NN / 4, dim3(64, 4), 0, stream>>>(q, kv, ebias_s, sorted_es,
                                                        offsets, agg);
        node_update_kernel<<<NN / 16, 256, 0, stream>>>(h, agg,
                                                        WT_hi_l + 3 * 4096,
                                                        WT_lo_l + 3 * 4096,
                                                        gn_l, bn_l, hb);
        // layer 0: full edge update; layer 1: bias-only; layer 2: skipped
        if (layer < L - 1) {
            const float* We_next = We + (layer + 1) * DE * H;
            edge_update_mfma_kernel<<<NE / 256, 256, 0, stream>>>(hb, eb_s, sorted_es,
                                                                  sorted_dst, Wt_l,
                                                                  bem_l, ge_l, be_l,
                                                                  We_next, ebias_s,
                                                                  1, layer == 0 ? 1 : 0);
        }
    }
}